// Round 1
// baseline (474.469 us; speedup 1.0000x reference)
//
#include <hip/hip_runtime.h>
#include <stdint.h>

typedef short bf16x4 __attribute__((ext_vector_type(4)));
typedef short bf16x8 __attribute__((ext_vector_type(8)));
typedef _Float16 f16x8 __attribute__((ext_vector_type(8)));
typedef float f32x4 __attribute__((ext_vector_type(4)));
typedef float f32x16 __attribute__((ext_vector_type(16)));

// ---------- helpers ----------
__device__ __forceinline__ short f2bf(float f) {  // RNE f32->bf16 (finite inputs)
  union { float f; uint32_t u; } v; v.f = f;
  uint32_t r = (v.u + 0x7fffu + ((v.u >> 16) & 1u)) >> 16;
  return (short)(uint16_t)r;
}

__device__ __forceinline__ f32x16 zero16() {
  f32x16 z;
#pragma unroll
  for (int i = 0; i < 16; ++i) z[i] = 0.f;
  return z;
}

__device__ __forceinline__ void gld_lds16(const void* g, void* l) {
  __builtin_amdgcn_global_load_lds(
      (__attribute__((address_space(1))) const void*)g,
      (__attribute__((address_space(3))) void*)l, 16, 0, 0);
}

// ---------- RMSNorm + cast to bf16 ----------
__global__ __launch_bounds__(256) void k_rmsnorm(const float* __restrict__ x,
                                                 const float* __restrict__ wn,
                                                 short* __restrict__ xn) {
  const int row = blockIdx.x;      // 8192 rows
  const int t = threadIdx.x;       // 256 threads, 4 floats each
  const float4 v = reinterpret_cast<const float4*>(x + (size_t)row * 1024)[t];
  float ss = v.x * v.x + v.y * v.y + v.z * v.z + v.w * v.w;
#pragma unroll
  for (int m = 32; m >= 1; m >>= 1) ss += __shfl_xor(ss, m, 64);
  __shared__ float red[4];
  if ((t & 63) == 0) red[t >> 6] = ss;
  __syncthreads();
  const float tot = red[0] + red[1] + red[2] + red[3];
  const float rr = rsqrtf(tot * (1.0f / 1024.0f) + 1e-5f);
  const float4 g = reinterpret_cast<const float4*>(wn)[t];
  bf16x4 o;
  o[0] = f2bf(v.x * rr * g.x);
  o[1] = f2bf(v.y * rr * g.y);
  o[2] = f2bf(v.z * rr * g.z);
  o[3] = f2bf(v.w * rr * g.w);
  reinterpret_cast<bf16x4*>(xn + (size_t)row * 1024)[t] = o;
}

// ---------- casts ----------
__global__ __launch_bounds__(256) void k_cast_bf(const float* __restrict__ in,
                                                 short* __restrict__ out, int n4) {
  int i = blockIdx.x * 256 + threadIdx.x;
  if (i >= n4) return;
  float4 v = reinterpret_cast<const float4*>(in)[i];
  bf16x4 o;
  o[0] = f2bf(v.x); o[1] = f2bf(v.y); o[2] = f2bf(v.z); o[3] = f2bf(v.w);
  reinterpret_cast<bf16x4*>(out)[i] = o;
}

__global__ __launch_bounds__(256) void k_cast_f16(const float* __restrict__ in,
                                                  _Float16* __restrict__ out, int n4) {
  int i = blockIdx.x * 256 + threadIdx.x;
  if (i >= n4) return;
  float4 v = reinterpret_cast<const float4*>(in)[i];
  _Float16 o[4] = {(_Float16)v.x, (_Float16)v.y, (_Float16)v.z, (_Float16)v.w};
  reinterpret_cast<ulong1*>(out)[i] = *reinterpret_cast<ulong1*>(o);
}

// ---------- QKV GEMM (bf16, m97 structure, 128x128xBK32) ----------
// C[m,n] = sum_k A[m,k]*B[n,k] + bias[n]; scatter to q/k/v [BH][S][64] bf16.
// q gets *0.125*log2(e) folded in (exp2-softmax).
__global__ __launch_bounds__(256) void k_gemm_qkv(const short* __restrict__ A,
                                                  const short* __restrict__ B,
                                                  const float* __restrict__ bias,
                                                  short* __restrict__ qb,
                                                  short* __restrict__ kb,
                                                  short* __restrict__ vb) {
  __shared__ __align__(16) short As[128 * 32];
  __shared__ __align__(16) short Bs[128 * 32];
  const int t = threadIdx.x;
  const long bm0 = (long)blockIdx.y * 128;
  const long bn0 = (long)blockIdx.x * 128;
  const int w = t >> 6, l = t & 63;
  const int wr = (w >> 1) * 64, wc = (w & 1) * 64;
  const int lm = l & 15, h = l >> 4;
  f32x4 acc[4][4];
#pragma unroll
  for (int i = 0; i < 4; ++i)
#pragma unroll
    for (int j = 0; j < 4; ++j) acc[i][j] = (f32x4){0.f, 0.f, 0.f, 0.f};
  const int srow = t >> 2, scol = (t & 3) * 8;
  const short* Ag = A + (bm0 + srow) * 1024 + scol;
  const short* Bg = B + (bn0 + srow) * 1024 + scol;
  short* AsP = As + t * 8;
  short* BsP = Bs + t * 8;
  for (int kt = 0; kt < 32; ++kt) {
    const int k0 = kt << 5;
    gld_lds16(Ag + k0, AsP);
    gld_lds16(Ag + k0 + 64 * 1024, AsP + 2048);
    gld_lds16(Bg + k0, BsP);
    gld_lds16(Bg + k0 + 64 * 1024, BsP + 2048);
    __syncthreads();
    bf16x8 af[4], bfr[4];
#pragma unroll
    for (int mi = 0; mi < 4; ++mi)
      af[mi] = *reinterpret_cast<const bf16x8*>(As + (wr + mi * 16 + lm) * 32 + h * 8);
#pragma unroll
    for (int ni = 0; ni < 4; ++ni)
      bfr[ni] = *reinterpret_cast<const bf16x8*>(Bs + (wc + ni * 16 + lm) * 32 + h * 8);
#pragma unroll
    for (int mi = 0; mi < 4; ++mi)
#pragma unroll
      for (int ni = 0; ni < 4; ++ni)
        acc[mi][ni] = __builtin_amdgcn_mfma_f32_16x16x32_bf16(af[mi], bfr[ni], acc[mi][ni], 0, 0, 0);
    __syncthreads();
  }
  // epilogue: C row = (l>>4)*4+reg, col = l&15 (m89-verified layout)
#pragma unroll
  for (int ni = 0; ni < 4; ++ni) {
    const int ncol = (int)bn0 + wc + ni * 16 + lm;
    const float bv = bias[ncol];
    const int which = ncol >> 10;
    const int e = ncol & 1023;
#pragma unroll
    for (int mi = 0; mi < 4; ++mi) {
#pragma unroll
      for (int r = 0; r < 4; ++r) {
        const long mrow = bm0 + wr + mi * 16 + h * 4 + r;
        const float val = acc[mi][ni][r] + bv;
        const long off = (((mrow >> 11) * 16 + (e >> 6)) * 2048 + (mrow & 2047)) * 64 + (e & 63);
        if (which == 0) qb[off] = f2bf(val * 0.18033688011112042f);  // 0.125*log2(e)
        else if (which == 1) kb[off] = f2bf(val);
        else vb[off] = f2bf(val);
      }
    }
  }
}

// ---------- out-proj GEMM (fp16 inputs for precision, fp32 out) ----------
__global__ __launch_bounds__(256) void k_gemm_out(const _Float16* __restrict__ A,
                                                  const _Float16* __restrict__ B,
                                                  const float* __restrict__ bias,
                                                  float* __restrict__ outp) {
  __shared__ __align__(16) _Float16 As[128 * 32];
  __shared__ __align__(16) _Float16 Bs[128 * 32];
  const int t = threadIdx.x;
  const long bm0 = (long)blockIdx.y * 128;
  const long bn0 = (long)blockIdx.x * 128;
  const int w = t >> 6, l = t & 63;
  const int wr = (w >> 1) * 64, wc = (w & 1) * 64;
  const int lm = l & 15, h = l >> 4;
  f32x4 acc[4][4];
#pragma unroll
  for (int i = 0; i < 4; ++i)
#pragma unroll
    for (int j = 0; j < 4; ++j) acc[i][j] = (f32x4){0.f, 0.f, 0.f, 0.f};
  const int srow = t >> 2, scol = (t & 3) * 8;
  const _Float16* Ag = A + (bm0 + srow) * 1024 + scol;
  const _Float16* Bg = B + (bn0 + srow) * 1024 + scol;
  _Float16* AsP = As + t * 8;
  _Float16* BsP = Bs + t * 8;
  for (int kt = 0; kt < 32; ++kt) {
    const int k0 = kt << 5;
    gld_lds16(Ag + k0, AsP);
    gld_lds16(Ag + k0 + 64 * 1024, AsP + 2048);
    gld_lds16(Bg + k0, BsP);
    gld_lds16(Bg + k0 + 64 * 1024, BsP + 2048);
    __syncthreads();
    f16x8 af[4], bfr[4];
#pragma unroll
    for (int mi = 0; mi < 4; ++mi)
      af[mi] = *reinterpret_cast<const f16x8*>(As + (wr + mi * 16 + lm) * 32 + h * 8);
#pragma unroll
    for (int ni = 0; ni < 4; ++ni)
      bfr[ni] = *reinterpret_cast<const f16x8*>(Bs + (wc + ni * 16 + lm) * 32 + h * 8);
#pragma unroll
    for (int mi = 0; mi < 4; ++mi)
#pragma unroll
      for (int ni = 0; ni < 4; ++ni)
        acc[mi][ni] = __builtin_amdgcn_mfma_f32_16x16x32_f16(af[mi], bfr[ni], acc[mi][ni], 0, 0, 0);
    __syncthreads();
  }
#pragma unroll
  for (int ni = 0; ni < 4; ++ni) {
    const int ncol = (int)bn0 + wc + ni * 16 + lm;
    const float bv = bias[ncol];
#pragma unroll
    for (int mi = 0; mi < 4; ++mi) {
#pragma unroll
      for (int r = 0; r < 4; ++r) {
        const long mrow = bm0 + wr + mi * 16 + h * 4 + r;
        outp[mrow * 1024 + ncol] = acc[mi][ni][r] + bv;
      }
    }
  }
}

// ---------- V transpose: v[BH][S][64] -> vT[BH][64][S] ----------
__global__ __launch_bounds__(256) void k_transpose_v(const short* __restrict__ v,
                                                     short* __restrict__ vt) {
  __shared__ short tile[64][72];
  const int bh = blockIdx.y, st = blockIdx.x;  // 32 s-tiles of 64
  const int t = threadIdx.x;
  const int r = t >> 2, c0 = (t & 3) * 16;
  const short* src = v + ((size_t)(bh * 2048 + st * 64 + r)) * 64 + c0;
  bf16x8 a = *reinterpret_cast<const bf16x8*>(src);
  bf16x8 b = *reinterpret_cast<const bf16x8*>(src + 8);
#pragma unroll
  for (int j = 0; j < 8; ++j) tile[r][c0 + j] = a[j];
#pragma unroll
  for (int j = 0; j < 8; ++j) tile[r][c0 + 8 + j] = b[j];
  __syncthreads();
  __align__(16) short tmp[16];
#pragma unroll
  for (int j = 0; j < 16; ++j) tmp[j] = tile[c0 + j][r];
  short* dst = vt + ((size_t)(bh * 64 + r)) * 2048 + st * 64 + c0;
  *reinterpret_cast<bf16x8*>(dst) = *reinterpret_cast<const bf16x8*>(tmp);
  *reinterpret_cast<bf16x8*>(dst + 8) = *reinterpret_cast<const bf16x8*>(tmp + 8);
}

// ---------- flash attention (swapped QK^T, 32x32x16 MFMA, no LDS) ----------
// Per wave: 32 q-rows. S^T = mfma(K, Q^T) -> lane holds 16 keys for q=lane&31.
// P^T feeds PV as B-operand by pure register repack (reg = j + 8*kg).
__global__ __launch_bounds__(256) void k_attn(const short* __restrict__ q,
                                              const short* __restrict__ k,
                                              const short* __restrict__ vt,
                                              _Float16* __restrict__ o) {
  const int bh = blockIdx.y;   // 64
  const int qt = blockIdx.x;   // 16
  const int t = threadIdx.x;
  const int w = t >> 6, l = t & 63;
  const int lq = l & 31, hh = l >> 5;
  const int qrow = qt * 128 + w * 32 + lq;
  const short* qp = q + ((size_t)(bh * 2048 + qrow)) * 64 + hh * 8;
  bf16x8 qf[4];
#pragma unroll
  for (int db = 0; db < 4; ++db) qf[db] = *reinterpret_cast<const bf16x8*>(qp + db * 16);
  f32x16 oa0 = zero16(), oa1 = zero16();
  float mr = -1e30f, lr = 0.f;
  const short* kp0 = k + ((size_t)bh * 2048 + lq) * 64 + hh * 8;
  const short* vp0 = vt + (size_t)bh * 64 * 2048 + (size_t)lq * 2048 + 4 * hh;
  for (int kt = 0; kt < 64; ++kt) {
    const short* kp = kp0 + (size_t)kt * 32 * 64;
    f32x16 s = zero16();
#pragma unroll
    for (int db = 0; db < 4; ++db) {
      bf16x8 kf = *reinterpret_cast<const bf16x8*>(kp + db * 16);
      s = __builtin_amdgcn_mfma_f32_32x32x16_bf16(kf, qf[db], s, 0, 0, 0);
    }
    float tm = s[0];
#pragma unroll
    for (int r2 = 1; r2 < 16; ++r2) tm = fmaxf(tm, s[r2]);
    tm = fmaxf(tm, __shfl_xor(tm, 32, 64));
    const float mn = fmaxf(mr, tm);
    const float corr = exp2f(mr - mn);
    float p[16];
    float ts = 0.f;
#pragma unroll
    for (int r2 = 0; r2 < 16; ++r2) { p[r2] = exp2f(s[r2] - mn); ts += p[r2]; }
    ts += __shfl_xor(ts, 32, 64);
    lr = lr * corr + ts;
    mr = mn;
#pragma unroll
    for (int r2 = 0; r2 < 16; ++r2) { oa0[r2] *= corr; oa1[r2] *= corr; }
    bf16x8 pf0, pf1;
#pragma unroll
    for (int j = 0; j < 8; ++j) { pf0[j] = f2bf(p[j]); pf1[j] = f2bf(p[j + 8]); }
    const short* vk = vp0 + kt * 32;
    {  // d-tile 0 (d = lq)
      bf16x4 x0 = *reinterpret_cast<const bf16x4*>(vk);
      bf16x4 x1 = *reinterpret_cast<const bf16x4*>(vk + 8);
      bf16x8 vf = __builtin_shufflevector(x0, x1, 0, 1, 2, 3, 4, 5, 6, 7);
      oa0 = __builtin_amdgcn_mfma_f32_32x32x16_bf16(vf, pf0, oa0, 0, 0, 0);
      bf16x4 y0 = *reinterpret_cast<const bf16x4*>(vk + 16);
      bf16x4 y1 = *reinterpret_cast<const bf16x4*>(vk + 24);
      vf = __builtin_shufflevector(y0, y1, 0, 1, 2, 3, 4, 5, 6, 7);
      oa0 = __builtin_amdgcn_mfma_f32_32x32x16_bf16(vf, pf1, oa0, 0, 0, 0);
    }
    {  // d-tile 1 (d = 32 + lq)
      const short* vk1 = vk + 32 * 2048;
      bf16x4 x0 = *reinterpret_cast<const bf16x4*>(vk1);
      bf16x4 x1 = *reinterpret_cast<const bf16x4*>(vk1 + 8);
      bf16x8 vf = __builtin_shufflevector(x0, x1, 0, 1, 2, 3, 4, 5, 6, 7);
      oa1 = __builtin_amdgcn_mfma_f32_32x32x16_bf16(vf, pf0, oa1, 0, 0, 0);
      bf16x4 y0 = *reinterpret_cast<const bf16x4*>(vk1 + 16);
      bf16x4 y1 = *reinterpret_cast<const bf16x4*>(vk1 + 24);
      vf = __builtin_shufflevector(y0, y1, 0, 1, 2, 3, 4, 5, 6, 7);
      oa1 = __builtin_amdgcn_mfma_f32_32x32x16_bf16(vf, pf1, oa1, 0, 0, 0);
    }
  }
  const float inv = 1.0f / lr;
  const int b = bh >> 4, hd = bh & 15;
  _Float16* ob = o + ((size_t)(b * 2048 + qrow)) * 1024 + hd * 64;
#pragma unroll
  for (int r2 = 0; r2 < 16; ++r2) {
    const int d0 = (r2 & 3) + 8 * (r2 >> 2) + 4 * hh;  // m74/m101 C layout
    ob[d0] = (_Float16)(oa0[r2] * inv);
    ob[d0 + 32] = (_Float16)(oa1[r2] * inv);
  }
}

// ---------- launch ----------
extern "C" void kernel_launch(void* const* d_in, const int* in_sizes, int n_in,
                              void* d_out, int out_size, void* d_ws, size_t ws_size,
                              hipStream_t stream) {
  const float* x = (const float*)d_in[0];
  const float* w_in = (const float*)d_in[1];
  const float* b_in = (const float*)d_in[2];
  const float* w_norm = (const float*)d_in[3];
  const float* w_out = (const float*)d_in[4];
  const float* b_out = (const float*)d_in[5];
  float* out = (float*)d_out;
  char* ws = (char*)d_ws;
  // workspace layout (88 MB total)
  short* xn = (short*)(ws);                       // 16 MB [8192][1024] bf16
  short* win_b = (short*)(ws + 16777216);         // 6 MB  [3072][1024] bf16
  _Float16* wout_h = (_Float16*)(ws + 23068672);  // 2 MB  [1024][1024] f16
  short* qb = (short*)(ws + 25165824);            // 16 MB [64][2048][64] bf16
  short* kb = (short*)(ws + 41943040);            // 16 MB
  short* vb = (short*)(ws + 58720256);            // 16 MB
  short* vt = (short*)(ws + 75497472);            // 16 MB [64][64][2048]
  _Float16* ob = (_Float16*)vb;                   // alias: v dead after transpose

  k_cast_bf<<<3072, 256, 0, stream>>>(w_in, win_b, 786432);
  k_cast_f16<<<1024, 256, 0, stream>>>(w_out, wout_h, 262144);
  k_rmsnorm<<<8192, 256, 0, stream>>>(x, w_norm, xn);
  k_gemm_qkv<<<dim3(24, 64), 256, 0, stream>>>(xn, win_b, b_in, qb, kb, vb);
  k_transpose_v<<<dim3(32, 64), 256, 0, stream>>>(vb, vt);
  k_attn<<<dim3(16, 64), 256, 0, stream>>>(qb, kb, vt, ob);
  k_gemm_out<<<dim3(8, 64), 256, 0, stream>>>(ob, wout_h, b_out, out);
}

// Round 2
// 241.585 us; speedup vs baseline: 1.9640x; 1.9640x over previous
//
#include <hip/hip_runtime.h>
#include <stdint.h>

typedef short bf16x4 __attribute__((ext_vector_type(4)));
typedef short bf16x8 __attribute__((ext_vector_type(8)));
typedef _Float16 f16x8 __attribute__((ext_vector_type(8)));
typedef float f32x4 __attribute__((ext_vector_type(4)));
typedef float f32x16 __attribute__((ext_vector_type(16)));
typedef unsigned int u32x4 __attribute__((ext_vector_type(4)));

#if __has_builtin(__builtin_amdgcn_exp2f)
#define EXP2 __builtin_amdgcn_exp2f
#else
#define EXP2 exp2f
#endif

// ---------- helpers ----------
__device__ __forceinline__ short f2bf(float f) {  // RNE f32->bf16 (finite inputs)
  union { float f; uint32_t u; } v; v.f = f;
  uint32_t r = (v.u + 0x7fffu + ((v.u >> 16) & 1u)) >> 16;
  return (short)(uint16_t)r;
}

__device__ __forceinline__ unsigned cvtpk_bf16(float lo, float hi) {
  unsigned r;
  asm("v_cvt_pk_bf16_f32 %0, %1, %2" : "=v"(r) : "v"(lo), "v"(hi));
  return r;
}

__device__ __forceinline__ f32x16 zero16() {
  f32x16 z;
#pragma unroll
  for (int i = 0; i < 16; ++i) z[i] = 0.f;
  return z;
}

__device__ __forceinline__ void gld_lds16(const void* g, void* l) {
  __builtin_amdgcn_global_load_lds(
      (__attribute__((address_space(1))) const void*)g,
      (__attribute__((address_space(3))) void*)l, 16, 0, 0);
}

// ---------- RMSNorm + cast to bf16 ----------
__global__ __launch_bounds__(256) void k_rmsnorm(const float* __restrict__ x,
                                                 const float* __restrict__ wn,
                                                 short* __restrict__ xn) {
  const int row = blockIdx.x;      // 8192 rows
  const int t = threadIdx.x;       // 256 threads, 4 floats each
  const float4 v = reinterpret_cast<const float4*>(x + (size_t)row * 1024)[t];
  float ss = v.x * v.x + v.y * v.y + v.z * v.z + v.w * v.w;
#pragma unroll
  for (int m = 32; m >= 1; m >>= 1) ss += __shfl_xor(ss, m, 64);
  __shared__ float red[4];
  if ((t & 63) == 0) red[t >> 6] = ss;
  __syncthreads();
  const float tot = red[0] + red[1] + red[2] + red[3];
  const float rr = rsqrtf(tot * (1.0f / 1024.0f) + 1e-5f);
  const float4 g = reinterpret_cast<const float4*>(wn)[t];
  bf16x4 o;
  o[0] = f2bf(v.x * rr * g.x);
  o[1] = f2bf(v.y * rr * g.y);
  o[2] = f2bf(v.z * rr * g.z);
  o[3] = f2bf(v.w * rr * g.w);
  reinterpret_cast<bf16x4*>(xn + (size_t)row * 1024)[t] = o;
}

// ---------- casts ----------
__global__ __launch_bounds__(256) void k_cast_bf(const float* __restrict__ in,
                                                 short* __restrict__ out, int n4) {
  int i = blockIdx.x * 256 + threadIdx.x;
  if (i >= n4) return;
  float4 v = reinterpret_cast<const float4*>(in)[i];
  bf16x4 o;
  o[0] = f2bf(v.x); o[1] = f2bf(v.y); o[2] = f2bf(v.z); o[3] = f2bf(v.w);
  reinterpret_cast<bf16x4*>(out)[i] = o;
}

__global__ __launch_bounds__(256) void k_cast_f16(const float* __restrict__ in,
                                                  _Float16* __restrict__ out, int n4) {
  int i = blockIdx.x * 256 + threadIdx.x;
  if (i >= n4) return;
  float4 v = reinterpret_cast<const float4*>(in)[i];
  _Float16 o[4] = {(_Float16)v.x, (_Float16)v.y, (_Float16)v.z, (_Float16)v.w};
  reinterpret_cast<ulong1*>(out)[i] = *reinterpret_cast<ulong1*>(o);
}

// ---------- QKV GEMM (bf16, m97 structure, 128x128xBK32) ----------
__global__ __launch_bounds__(256) void k_gemm_qkv(const short* __restrict__ A,
                                                  const short* __restrict__ B,
                                                  const float* __restrict__ bias,
                                                  short* __restrict__ qb,
                                                  short* __restrict__ kb,
                                                  short* __restrict__ vb) {
  __shared__ __align__(16) short As[128 * 32];
  __shared__ __align__(16) short Bs[128 * 32];
  const int t = threadIdx.x;
  const long bm0 = (long)blockIdx.y * 128;
  const long bn0 = (long)blockIdx.x * 128;
  const int w = t >> 6, l = t & 63;
  const int wr = (w >> 1) * 64, wc = (w & 1) * 64;
  const int lm = l & 15, h = l >> 4;
  f32x4 acc[4][4];
#pragma unroll
  for (int i = 0; i < 4; ++i)
#pragma unroll
    for (int j = 0; j < 4; ++j) acc[i][j] = (f32x4){0.f, 0.f, 0.f, 0.f};
  const int srow = t >> 2, scol = (t & 3) * 8;
  const short* Ag = A + (bm0 + srow) * 1024 + scol;
  const short* Bg = B + (bn0 + srow) * 1024 + scol;
  short* AsP = As + t * 8;
  short* BsP = Bs + t * 8;
  for (int kt = 0; kt < 32; ++kt) {
    const int k0 = kt << 5;
    gld_lds16(Ag + k0, AsP);
    gld_lds16(Ag + k0 + 64 * 1024, AsP + 2048);
    gld_lds16(Bg + k0, BsP);
    gld_lds16(Bg + k0 + 64 * 1024, BsP + 2048);
    __syncthreads();
    bf16x8 af[4], bfr[4];
#pragma unroll
    for (int mi = 0; mi < 4; ++mi)
      af[mi] = *reinterpret_cast<const bf16x8*>(As + (wr + mi * 16 + lm) * 32 + h * 8);
#pragma unroll
    for (int ni = 0; ni < 4; ++ni)
      bfr[ni] = *reinterpret_cast<const bf16x8*>(Bs + (wc + ni * 16 + lm) * 32 + h * 8);
#pragma unroll
    for (int mi = 0; mi < 4; ++mi)
#pragma unroll
      for (int ni = 0; ni < 4; ++ni)
        acc[mi][ni] = __builtin_amdgcn_mfma_f32_16x16x32_bf16(af[mi], bfr[ni], acc[mi][ni], 0, 0, 0);
    __syncthreads();
  }
#pragma unroll
  for (int ni = 0; ni < 4; ++ni) {
    const int ncol = (int)bn0 + wc + ni * 16 + lm;
    const float bv = bias[ncol];
    const int which = ncol >> 10;
    const int e = ncol & 1023;
#pragma unroll
    for (int mi = 0; mi < 4; ++mi) {
#pragma unroll
      for (int r = 0; r < 4; ++r) {
        const long mrow = bm0 + wr + mi * 16 + h * 4 + r;
        const float val = acc[mi][ni][r] + bv;
        const long off = (((mrow >> 11) * 16 + (e >> 6)) * 2048 + (mrow & 2047)) * 64 + (e & 63);
        if (which == 0) qb[off] = f2bf(val * 0.18033688011112042f);  // 0.125*log2(e)
        else if (which == 1) kb[off] = f2bf(val);
        else vb[off] = f2bf(val);
      }
    }
  }
}

// ---------- out-proj GEMM (fp16 inputs for precision, fp32 out) ----------
__global__ __launch_bounds__(256) void k_gemm_out(const _Float16* __restrict__ A,
                                                  const _Float16* __restrict__ B,
                                                  const float* __restrict__ bias,
                                                  float* __restrict__ outp) {
  __shared__ __align__(16) _Float16 As[128 * 32];
  __shared__ __align__(16) _Float16 Bs[128 * 32];
  const int t = threadIdx.x;
  const long bm0 = (long)blockIdx.y * 128;
  const long bn0 = (long)blockIdx.x * 128;
  const int w = t >> 6, l = t & 63;
  const int wr = (w >> 1) * 64, wc = (w & 1) * 64;
  const int lm = l & 15, h = l >> 4;
  f32x4 acc[4][4];
#pragma unroll
  for (int i = 0; i < 4; ++i)
#pragma unroll
    for (int j = 0; j < 4; ++j) acc[i][j] = (f32x4){0.f, 0.f, 0.f, 0.f};
  const int srow = t >> 2, scol = (t & 3) * 8;
  const _Float16* Ag = A + (bm0 + srow) * 1024 + scol;
  const _Float16* Bg = B + (bn0 + srow) * 1024 + scol;
  _Float16* AsP = As + t * 8;
  _Float16* BsP = Bs + t * 8;
  for (int kt = 0; kt < 32; ++kt) {
    const int k0 = kt << 5;
    gld_lds16(Ag + k0, AsP);
    gld_lds16(Ag + k0 + 64 * 1024, AsP + 2048);
    gld_lds16(Bg + k0, BsP);
    gld_lds16(Bg + k0 + 64 * 1024, BsP + 2048);
    __syncthreads();
    f16x8 af[4], bfr[4];
#pragma unroll
    for (int mi = 0; mi < 4; ++mi)
      af[mi] = *reinterpret_cast<const f16x8*>(As + (wr + mi * 16 + lm) * 32 + h * 8);
#pragma unroll
    for (int ni = 0; ni < 4; ++ni)
      bfr[ni] = *reinterpret_cast<const f16x8*>(Bs + (wc + ni * 16 + lm) * 32 + h * 8);
#pragma unroll
    for (int mi = 0; mi < 4; ++mi)
#pragma unroll
      for (int ni = 0; ni < 4; ++ni)
        acc[mi][ni] = __builtin_amdgcn_mfma_f32_16x16x32_f16(af[mi], bfr[ni], acc[mi][ni], 0, 0, 0);
    __syncthreads();
  }
#pragma unroll
  for (int ni = 0; ni < 4; ++ni) {
    const int ncol = (int)bn0 + wc + ni * 16 + lm;
    const float bv = bias[ncol];
#pragma unroll
    for (int mi = 0; mi < 4; ++mi) {
#pragma unroll
      for (int r = 0; r < 4; ++r) {
        const long mrow = bm0 + wr + mi * 16 + h * 4 + r;
        outp[mrow * 1024 + ncol] = acc[mi][ni][r] + bv;
      }
    }
  }
}

// ---------- V transpose: v[BH][S][64] -> vT[BH][64][S] ----------
__global__ __launch_bounds__(256) void k_transpose_v(const short* __restrict__ v,
                                                     short* __restrict__ vt) {
  __shared__ short tile[64][72];
  const int bh = blockIdx.y, st = blockIdx.x;  // 32 s-tiles of 64
  const int t = threadIdx.x;
  const int r = t >> 2, c0 = (t & 3) * 16;
  const short* src = v + ((size_t)(bh * 2048 + st * 64 + r)) * 64 + c0;
  bf16x8 a = *reinterpret_cast<const bf16x8*>(src);
  bf16x8 b = *reinterpret_cast<const bf16x8*>(src + 8);
#pragma unroll
  for (int j = 0; j < 8; ++j) tile[r][c0 + j] = a[j];
#pragma unroll
  for (int j = 0; j < 8; ++j) tile[r][c0 + 8 + j] = b[j];
  __syncthreads();
  __align__(16) short tmp[16];
#pragma unroll
  for (int j = 0; j < 16; ++j) tmp[j] = tile[c0 + j][r];
  short* dst = vt + ((size_t)(bh * 64 + r)) * 2048 + st * 64 + c0;
  *reinterpret_cast<bf16x8*>(dst) = *reinterpret_cast<const bf16x8*>(tmp);
  *reinterpret_cast<bf16x8*>(dst + 8) = *reinterpret_cast<const bf16x8*>(tmp + 8);
}

// ---------- flash attention v2 ----------
// 4 waves/block, 128 q-rows/block (32/wave), KBLK=64, double-buffered LDS for
// K [64 key][64 d] and V^T [64 d][64 key], both XOR-swizzled on 16B granules
// (g ^= row&7) via pre-swizzled global_load_lds SOURCE addresses (LDS dest
// linear). Swapped QK^T (mfma(K,Q)); P->bf16 via v_cvt_pk_bf16_f32 +
// v_permlane32_swap_b32 (identity k-map => V frags are single ds_read_b128).
// Defer-max rescale (THR=8 in log2 domain; q pre-scaled by 0.125*log2e).
__global__ __launch_bounds__(256) void k_attn(const short* __restrict__ q,
                                              const short* __restrict__ k,
                                              const short* __restrict__ vt,
                                              _Float16* __restrict__ o) {
  __shared__ __align__(16) short Ks[2][4096];  // 8KB x2
  __shared__ __align__(16) short Vs[2][4096];  // 8KB x2
  const int bh = blockIdx.y;   // 64
  const int qt = blockIdx.x;   // 16
  const int t = threadIdx.x;
  const int w = t >> 6, l = t & 63;
  const int lq = l & 31, hh = l >> 5;
  const int xr = lq & 7;
  const int qrow = qt * 128 + w * 32 + lq;

  // Q fragments (B-operand of QK^T): lane holds Q[qrow][db*16 + 8*hh + j]
  const short* qp = q + ((size_t)(bh * 2048 + qrow)) * 64 + hh * 8;
  bf16x8 qf[4];
#pragma unroll
  for (int db = 0; db < 4; ++db) qf[db] = *reinterpret_cast<const bf16x8*>(qp + db * 16);

  // staging constants: each wave stages granules [w*128, w*128+128)
  const int gg0 = w * 128 + l, gg1 = gg0 + 64;
  const int u0 = gg0 ^ ((gg0 >> 3) & 7);   // swizzled source granule
  const int u1 = gg1 ^ ((gg1 >> 3) & 7);
  const short* kh = k + (size_t)bh * 2048 * 64;
  const short* vh = vt + (size_t)bh * 64 * 2048;
  const short* ksrc0 = kh + u0 * 8;
  const short* ksrc1 = kh + u1 * 8;
  const short* vsrc0 = vh + (gg0 >> 3) * 2048 + (u0 & 7) * 8;
  const short* vsrc1 = vh + (gg1 >> 3) * 2048 + (u1 & 7) * 8;

  // swizzled LDS read offsets (shorts)
  int koff[2][4], voff[2][4];
#pragma unroll
  for (int ks = 0; ks < 2; ++ks)
#pragma unroll
    for (int db = 0; db < 4; ++db)
      koff[ks][db] = ((ks * 32 + lq) * 8 + ((db * 2 + hh) ^ xr)) * 8;
#pragma unroll
  for (int dt = 0; dt < 2; ++dt)
#pragma unroll
    for (int kg = 0; kg < 4; ++kg)
      voff[dt][kg] = ((dt * 32 + lq) * 8 + ((kg * 2 + hh) ^ xr)) * 8;

  f32x16 oa0 = zero16(), oa1 = zero16();
  float mr = -1e30f, lr = 0.f;

  // prologue: stage tile 0
  gld_lds16(ksrc0, &Ks[0][gg0 * 8]);
  gld_lds16(ksrc1, &Ks[0][gg1 * 8]);
  gld_lds16(vsrc0, &Vs[0][gg0 * 8]);
  gld_lds16(vsrc1, &Vs[0][gg1 * 8]);
  __syncthreads();

  int cur = 0;
  for (int kt = 0; kt < 32; ++kt) {
    // stage next tile into other buffer (issue-early; wrap redundant at end)
    const int kn = (kt + 1) & 31;
    const int nb = cur ^ 1;
    gld_lds16(ksrc0 + kn * 4096, &Ks[nb][gg0 * 8]);
    gld_lds16(ksrc1 + kn * 4096, &Ks[nb][gg1 * 8]);
    gld_lds16(vsrc0 + kn * 64, &Vs[nb][gg0 * 8]);
    gld_lds16(vsrc1 + kn * 64, &Vs[nb][gg1 * 8]);

    const short* kb_ = Ks[cur];
    const short* vb_ = Vs[cur];
    // QK^T: s0 = keys 0..31, s1 = keys 32..63 (rows), q-col = lq
    f32x16 s0 = zero16(), s1 = zero16();
#pragma unroll
    for (int db = 0; db < 4; ++db) {
      bf16x8 kf = *reinterpret_cast<const bf16x8*>(kb_ + koff[0][db]);
      s0 = __builtin_amdgcn_mfma_f32_32x32x16_bf16(kf, qf[db], s0, 0, 0, 0);
    }
#pragma unroll
    for (int db = 0; db < 4; ++db) {
      bf16x8 kf = *reinterpret_cast<const bf16x8*>(kb_ + koff[1][db]);
      s1 = __builtin_amdgcn_mfma_f32_32x32x16_bf16(kf, qf[db], s1, 0, 0, 0);
    }
    // tile max (tree, depth 5)
    float m8[8];
#pragma unroll
    for (int i = 0; i < 8; ++i)
      m8[i] = fmaxf(fmaxf(s0[i], s0[i + 8]), fmaxf(s1[i], s1[i + 8]));
    float m4a = fmaxf(m8[0], m8[4]), m4b = fmaxf(m8[1], m8[5]);
    float m4c = fmaxf(m8[2], m8[6]), m4d = fmaxf(m8[3], m8[7]);
    float tm = fmaxf(fmaxf(m4a, m4b), fmaxf(m4c, m4d));
    tm = fmaxf(tm, __shfl_xor(tm, 32, 64));
    // defer-max rescale (log2 domain, THR=8 => P <= 256)
    if (!__all(tm <= mr + 8.f)) {
      const float mn = fmaxf(mr, tm);
      const float corr = EXP2(mr - mn);
      lr *= corr;
#pragma unroll
      for (int r = 0; r < 16; ++r) { oa0[r] *= corr; oa1[r] *= corr; }
      mr = mn;
    }
    // P = exp2(s - mr) in place, then row-sum (tree)
#pragma unroll
    for (int r = 0; r < 16; ++r) {
      s0[r] = EXP2(s0[r] - mr);
      s1[r] = EXP2(s1[r] - mr);
    }
    float a8[8];
#pragma unroll
    for (int i = 0; i < 8; ++i)
      a8[i] = (s0[i] + s0[i + 8]) + (s1[i] + s1[i + 8]);
    float ts = ((a8[0] + a8[4]) + (a8[1] + a8[5])) + ((a8[2] + a8[6]) + (a8[3] + a8[7]));
    ts += __shfl_xor(ts, 32, 64);
    lr += ts;
    // PV: per 16-key group build P-frag (identity k-map) and 2 V-frag mfmas
#pragma unroll
    for (int kg = 0; kg < 4; ++kg) {
      const f32x16& sv = (kg & 2) ? s1 : s0;
      const int b0 = (kg & 1) * 8;
      unsigned w0 = cvtpk_bf16(sv[b0 + 0], sv[b0 + 1]);
      unsigned w2 = cvtpk_bf16(sv[b0 + 4], sv[b0 + 5]);
      unsigned w1 = cvtpk_bf16(sv[b0 + 2], sv[b0 + 3]);
      unsigned w3 = cvtpk_bf16(sv[b0 + 6], sv[b0 + 7]);
      asm("v_permlane32_swap_b32 %0, %1" : "+v"(w0), "+v"(w2));
      asm("v_permlane32_swap_b32 %0, %1" : "+v"(w1), "+v"(w3));
      u32x4 pw = {w0, w1, w2, w3};
      bf16x8 pf = *reinterpret_cast<bf16x8*>(&pw);
      bf16x8 vf0 = *reinterpret_cast<const bf16x8*>(vb_ + voff[0][kg]);
      oa0 = __builtin_amdgcn_mfma_f32_32x32x16_bf16(vf0, pf, oa0, 0, 0, 0);
      bf16x8 vf1 = *reinterpret_cast<const bf16x8*>(vb_ + voff[1][kg]);
      oa1 = __builtin_amdgcn_mfma_f32_32x32x16_bf16(vf1, pf, oa1, 0, 0, 0);
    }
    __syncthreads();  // drains stage vmcnt + all lds reads of cur
    cur = nb;
  }
  const float inv = 1.0f / lr;
  const int b = bh >> 4, hd = bh & 15;
  _Float16* ob = o + ((size_t)(b * 2048 + qrow)) * 1024 + hd * 64;
#pragma unroll
  for (int r2 = 0; r2 < 16; ++r2) {
    const int d0 = (r2 & 3) + 8 * (r2 >> 2) + 4 * hh;  // 32x32 C layout
    ob[d0] = (_Float16)(oa0[r2] * inv);
    ob[d0 + 32] = (_Float16)(oa1[r2] * inv);
  }
}

// ---------- launch ----------
extern "C" void kernel_launch(void* const* d_in, const int* in_sizes, int n_in,
                              void* d_out, int out_size, void* d_ws, size_t ws_size,
                              hipStream_t stream) {
  const float* x = (const float*)d_in[0];
  const float* w_in = (const float*)d_in[1];
  const float* b_in = (const float*)d_in[2];
  const float* w_norm = (const float*)d_in[3];
  const float* w_out = (const float*)d_in[4];
  const float* b_out = (const float*)d_in[5];
  float* out = (float*)d_out;
  char* ws = (char*)d_ws;
  short* xn = (short*)(ws);                       // 16 MB [8192][1024] bf16
  short* win_b = (short*)(ws + 16777216);         // 6 MB  [3072][1024] bf16
  _Float16* wout_h = (_Float16*)(ws + 23068672);  // 2 MB  [1024][1024] f16
  short* qb = (short*)(ws + 25165824);            // 16 MB [64][2048][64] bf16
  short* kb = (short*)(ws + 41943040);            // 16 MB
  short* vb = (short*)(ws + 58720256);            // 16 MB
  short* vt = (short*)(ws + 75497472);            // 16 MB [64][64][2048]
  _Float16* ob = (_Float16*)vb;                   // alias: v dead after transpose

  k_cast_bf<<<3072, 256, 0, stream>>>(w_in, win_b, 786432);
  k_cast_f16<<<1024, 256, 0, stream>>>(w_out, wout_h, 262144);
  k_rmsnorm<<<8192, 256, 0, stream>>>(x, w_norm, xn);
  k_gemm_qkv<<<dim3(24, 64), 256, 0, stream>>>(xn, win_b, b_in, qb, kb, vb);
  k_transpose_v<<<dim3(32, 64), 256, 0, stream>>>(vb, vt);
  k_attn<<<dim3(16, 64), 256, 0, stream>>>(qb, kb, vt, ob);
  k_gemm_out<<<dim3(8, 64), 256, 0, stream>>>(ob, wout_h, b_out, out);
}